// Round 1
// baseline (396.494 us; speedup 1.0000x reference)
//
#include <hip/hip_runtime.h>
#include <hip/hip_bf16.h>
#include <math.h>

// Problem: ConvNeXt MLP + parallel MoE-LoRA, fp32 in/out, bf16-tolerance harness.
// B,H,W,C = 64,14,14,768 ; N_tok = 12544 = 98*128 ; HID = 3072 ; E=8,K=2,R=16.
//
// Decomposition:
//   h  = gelu(x @ w1 + b1)                     GEMM1  [12544,768]x[768,3072]
//   sd[n, e*16+r] = wt[n,e]*gelu(x @ wdown)    GEMMd  [12544,768]x[768,128]
//   out = [h | sd] @ [w2 ; wup_flat] + b2      GEMM2  [12544,3200]x[3200,768]
// (wt-scaling commutes with the linear up-projection; SCALING = 1.0)
//
// Workspace layout (bf16 elements):
//   xb   12544*768   = 19.27 MB
//   w1t   3072*768   =  4.72 MB   (w1 transposed -> Bt layout)
//   B2t   768*3200   =  4.92 MB   (rows c, cols k: w2^T | wup^T)
//   wdt    128*768   =  0.20 MB   (wdown packed+transposed -> Bt layout)
//   Ap  12544*3200   = 80.28 MB   (A' = [h | sd], row stride 3200)
//   total ~109.4 MB of d_ws.

#define NTOK   12544
#define CDIM   768
#define HIDDIM 3072
#define KBIG   3200

typedef __attribute__((ext_vector_type(8))) short bf16x8;
typedef __attribute__((ext_vector_type(4))) float f32x4;

__device__ inline unsigned short f2bf(float f) {
    unsigned int x = __float_as_uint(f);
    x += 0x7fffu + ((x >> 16) & 1u);   // RNE
    return (unsigned short)(x >> 16);
}

__device__ inline float gelu_exact(float v) {
    return 0.5f * v * (1.0f + erff(v * 0.70710678118654752f));
}

// ---------------- cast / layout kernels ----------------

__global__ void cast_x_kernel(const float* __restrict__ in,
                              unsigned short* __restrict__ out, int n4) {
    int i = blockIdx.x * 256 + threadIdx.x;
    if (i >= n4) return;
    float4 v = ((const float4*)in)[i];
    ushort4 o;
    o.x = f2bf(v.x); o.y = f2bf(v.y); o.z = f2bf(v.z); o.w = f2bf(v.w);
    ((ushort4*)out)[i] = o;
}

// out[(c0+i)][out_off + r0+tx] = in[(r0+tx)][(c0+i)]  — 32x32 LDS tile transpose
__global__ void transpose_cast_kernel(const float* __restrict__ in,
                                      unsigned short* __restrict__ out,
                                      int R, int Ccols, int out_ld, int out_off) {
    __shared__ float tile[32][33];
    int c0 = blockIdx.x * 32, r0 = blockIdx.y * 32;
    int tx = threadIdx.x, ty = threadIdx.y;
    for (int i = ty; i < 32; i += 8)
        tile[i][tx] = in[(size_t)(r0 + i) * Ccols + c0 + tx];
    __syncthreads();
    for (int i = ty; i < 32; i += 8)
        out[(size_t)(c0 + i) * out_ld + out_off + r0 + tx] = f2bf(tile[tx][i]);
}

// wdt[j][c] = w_down[e][c][r]  (j = e*16+r), w_down is [8][768][16] row-major
__global__ void pack_wdown_kernel(const float* __restrict__ in,
                                  unsigned short* __restrict__ out) {
    int idx = blockIdx.x * 256 + threadIdx.x;
    if (idx >= 128 * 768) return;
    int j = idx / 768, c = idx - j * 768;
    int e = j >> 4, r = j & 15;
    out[idx] = f2bf(in[((size_t)e * 768 + c) * 16 + r]);
}

// ---------------- MFMA GEMM, C = A * Bt^T, 128x128 tile, BK=32 ----------------
// EPI 0: h-epilogue   -> gelu(acc + b1[n]) -> bf16 Ap[m*3200 + n]
// EPI 1: down-epilogue-> wt[m, n>>4]*gelu(acc) -> bf16 Ap[m*3200 + 3072 + n]
// EPI 2: out-epilogue -> acc + b2[n] -> f32 out[m*768 + n]

template <int EPI>
__global__ void __launch_bounds__(256)
gemm_bt_kernel(const unsigned short* __restrict__ A, int lda,
               const unsigned short* __restrict__ Bt, int ldb,
               int kIters,
               const float* __restrict__ bias,
               unsigned short* __restrict__ apOut,
               float* __restrict__ fOut,
               const int* __restrict__ tki,
               const float* __restrict__ tkp) {
    __shared__ __align__(16) unsigned short As[128 * 32];
    __shared__ __align__(16) unsigned short Bs[128 * 32];

    const int tid  = threadIdx.x;
    const int lane = tid & 63;
    const int wave = tid >> 6;
    const int m0 = blockIdx.y * 128;
    const int n0 = blockIdx.x * 128;
    const int wm = (wave >> 1) * 64;
    const int wn = (wave & 1) * 64;
    const int row16 = lane & 15;
    const int kch   = (lane >> 4) * 8;
    const int quad  = lane >> 4;

    f32x4 acc[4][4] = {};

    for (int kt = 0; kt < kIters; ++kt) {
        const int k0 = kt * 32;
        // stage A tile [128][32] and Bt tile [128][32], row-major, 16B chunks
        #pragma unroll
        for (int q = 0; q < 2; ++q) {
            int ci = q * 256 + tid;          // 0..511
            int r  = ci >> 2;                // tile row
            int c  = (ci & 3) * 8;           // k offset (bf16 elems)
            uint4 va = *(const uint4*)(A  + (size_t)(m0 + r) * lda + k0 + c);
            uint4 vb = *(const uint4*)(Bt + (size_t)(n0 + r) * ldb + k0 + c);
            *(uint4*)&As[ci * 8] = va;
            *(uint4*)&Bs[ci * 8] = vb;
        }
        __syncthreads();

        bf16x8 af[4], bfr[4];
        #pragma unroll
        for (int mi = 0; mi < 4; ++mi)
            af[mi] = *(const bf16x8*)&As[(wm + mi * 16 + row16) * 32 + kch];
        #pragma unroll
        for (int ni = 0; ni < 4; ++ni)
            bfr[ni] = *(const bf16x8*)&Bs[(wn + ni * 16 + row16) * 32 + kch];

        #pragma unroll
        for (int mi = 0; mi < 4; ++mi)
            #pragma unroll
            for (int ni = 0; ni < 4; ++ni)
                acc[mi][ni] = __builtin_amdgcn_mfma_f32_16x16x32_bf16(
                    af[mi], bfr[ni], acc[mi][ni], 0, 0, 0);
        __syncthreads();
    }

    // epilogue: lane holds col = row16, rows quad*4 + i (i = reg idx)
    #pragma unroll
    for (int mi = 0; mi < 4; ++mi) {
        #pragma unroll
        for (int i = 0; i < 4; ++i) {
            const int m = m0 + wm + mi * 16 + quad * 4 + i;
            int i0 = 0, i1 = 0; float p0 = 0.f, p1 = 0.f;
            if (EPI == 1) {
                i0 = tki[m * 2]; i1 = tki[m * 2 + 1];
                p0 = tkp[m * 2]; p1 = tkp[m * 2 + 1];
            }
            #pragma unroll
            for (int ni = 0; ni < 4; ++ni) {
                const int ncol = n0 + wn + ni * 16 + row16;
                float v = acc[mi][ni][i];
                if (EPI == 0) {
                    v = gelu_exact(v + bias[ncol]);
                    apOut[(size_t)m * KBIG + ncol] = f2bf(v);
                } else if (EPI == 1) {
                    const int e = ncol >> 4;
                    float wt = (i0 == e ? p0 : 0.f) + (i1 == e ? p1 : 0.f);
                    v = gelu_exact(v) * wt;
                    apOut[(size_t)m * KBIG + 3072 + ncol] = f2bf(v);
                } else {
                    fOut[(size_t)m * CDIM + ncol] = v + bias[ncol];
                }
            }
        }
    }
}

// ---------------- launch ----------------

extern "C" void kernel_launch(void* const* d_in, const int* in_sizes, int n_in,
                              void* d_out, int out_size, void* d_ws, size_t ws_size,
                              hipStream_t stream) {
    const float* x   = (const float*)d_in[0];
    const float* tkp = (const float*)d_in[1];
    const int*   tki = (const int*)d_in[2];
    const float* w1  = (const float*)d_in[3];
    const float* b1  = (const float*)d_in[4];
    const float* w2  = (const float*)d_in[5];
    const float* b2  = (const float*)d_in[6];
    const float* wdn = (const float*)d_in[7];
    const float* wup = (const float*)d_in[8];
    float* out = (float*)d_out;

    unsigned short* xb  = (unsigned short*)d_ws;
    unsigned short* w1t = xb  + (size_t)NTOK * CDIM;
    unsigned short* B2t = w1t + (size_t)HIDDIM * CDIM;
    unsigned short* wdt = B2t + (size_t)CDIM * KBIG;
    unsigned short* Ap  = wdt + (size_t)128 * CDIM;

    // casts / layout
    {
        int n4 = (NTOK * CDIM) / 4;
        cast_x_kernel<<<(n4 + 255) / 256, 256, 0, stream>>>(x, xb, n4);
    }
    dim3 tb(32, 8);
    // w1 [768][3072] -> w1t [3072][768]
    transpose_cast_kernel<<<dim3(HIDDIM / 32, CDIM / 32), tb, 0, stream>>>(
        w1, w1t, CDIM, HIDDIM, CDIM, 0);
    // w2 [3072][768] -> B2t[:, 0:3072]
    transpose_cast_kernel<<<dim3(CDIM / 32, HIDDIM / 32), tb, 0, stream>>>(
        w2, B2t, HIDDIM, CDIM, KBIG, 0);
    // w_up flat [128][768] -> B2t[:, 3072:3200]
    transpose_cast_kernel<<<dim3(CDIM / 32, 128 / 32), tb, 0, stream>>>(
        wup, B2t, 128, CDIM, KBIG, 3072);
    pack_wdown_kernel<<<(128 * 768 + 255) / 256, 256, 0, stream>>>(wdn, wdt);

    // GEMMd: sd -> Ap[:, 3072:3200]
    gemm_bt_kernel<1><<<dim3(1, NTOK / 128), 256, 0, stream>>>(
        xb, CDIM, wdt, CDIM, CDIM / 32, nullptr, Ap, nullptr, tki, tkp);
    // GEMM1: h -> Ap[:, 0:3072]
    gemm_bt_kernel<0><<<dim3(HIDDIM / 128, NTOK / 128), 256, 0, stream>>>(
        xb, CDIM, w1t, CDIM, CDIM / 32, b1, Ap, nullptr, nullptr, nullptr);
    // GEMM2: out = Ap @ B2t^T + b2
    gemm_bt_kernel<2><<<dim3(CDIM / 128, NTOK / 128), 256, 0, stream>>>(
        Ap, KBIG, B2t, KBIG, KBIG / 32, b2, nullptr, out, nullptr, nullptr);
}

// Round 2
// 392.205 us; speedup vs baseline: 1.0109x; 1.0109x over previous
//
#include <hip/hip_runtime.h>
#include <hip/hip_bf16.h>
#include <math.h>

// ConvNeXt MLP + parallel MoE-LoRA, fp32 in/out, bf16-tolerance harness.
// B,H,W,C = 64,14,14,768 ; N_tok = 12544 = 98*128 ; HID = 3072 ; E=8,K=2,R=16.
//
// Decomposition:
//   h  = gelu(x @ w1 + b1)                     GEMM1  [12544,768]x[768,3072]
//   sd[n, e*16+r] = wt[n,e]*gelu(x @ wdown)    GEMMd  [12544,768]x[768,128]
//   out = [h | sd] @ [w2 ; wup_flat] + b2      GEMM2  [12544,3200]x[3200,768]
// (wt-scaling commutes with the linear up-projection; SCALING = 1.0)
//
// R2: staging via __builtin_amdgcn_global_load_lds width=16 (m93->m97 lever).

#define NTOK   12544
#define CDIM   768
#define HIDDIM 3072
#define KBIG   3200

typedef __attribute__((ext_vector_type(8))) short bf16x8;
typedef __attribute__((ext_vector_type(4))) float f32x4;

#define GLOBAL_AS(p) ((const __attribute__((address_space(1))) void*)(p))
#define LDS_AS(p)    ((__attribute__((address_space(3))) void*)(p))

__device__ inline unsigned short f2bf(float f) {
    unsigned int x = __float_as_uint(f);
    x += 0x7fffu + ((x >> 16) & 1u);   // RNE
    return (unsigned short)(x >> 16);
}

__device__ inline float gelu_exact(float v) {
    return 0.5f * v * (1.0f + erff(v * 0.70710678118654752f));
}

// ---------------- cast / layout kernels ----------------

__global__ void cast_x_kernel(const float* __restrict__ in,
                              unsigned short* __restrict__ out, int n4) {
    int i = blockIdx.x * 256 + threadIdx.x;
    if (i >= n4) return;
    float4 v = ((const float4*)in)[i];
    ushort4 o;
    o.x = f2bf(v.x); o.y = f2bf(v.y); o.z = f2bf(v.z); o.w = f2bf(v.w);
    ((ushort4*)out)[i] = o;
}

// out[(c0+i)][out_off + r0+tx] = in[(r0+tx)][(c0+i)]  — 32x32 LDS tile transpose
__global__ void transpose_cast_kernel(const float* __restrict__ in,
                                      unsigned short* __restrict__ out,
                                      int R, int Ccols, int out_ld, int out_off) {
    __shared__ float tile[32][33];
    int c0 = blockIdx.x * 32, r0 = blockIdx.y * 32;
    int tx = threadIdx.x, ty = threadIdx.y;
    for (int i = ty; i < 32; i += 8)
        tile[i][tx] = in[(size_t)(r0 + i) * Ccols + c0 + tx];
    __syncthreads();
    for (int i = ty; i < 32; i += 8)
        out[(size_t)(c0 + i) * out_ld + out_off + r0 + tx] = f2bf(tile[tx][i]);
}

// wdt[j][c] = w_down[e][c][r]  (j = e*16+r), w_down is [8][768][16] row-major
__global__ void pack_wdown_kernel(const float* __restrict__ in,
                                  unsigned short* __restrict__ out) {
    int idx = blockIdx.x * 256 + threadIdx.x;
    if (idx >= 128 * 768) return;
    int j = idx / 768, c = idx - j * 768;
    int e = j >> 4, r = j & 15;
    out[idx] = f2bf(in[((size_t)e * 768 + c) * 16 + r]);
}

// ---------------- MFMA GEMM, C = A * Bt^T, 128x128 tile, BK=32 ----------------
// EPI 0: h-epilogue   -> gelu(acc + b1[n]) -> bf16 Ap[m*3200 + n]
// EPI 1: down-epilogue-> wt[m, n>>4]*gelu(acc) -> bf16 Ap[m*3200 + 3072 + n]
// EPI 2: out-epilogue -> acc + b2[n] -> f32 out[m*768 + n]

template <int EPI>
__global__ void __launch_bounds__(256)
gemm_bt_kernel(const unsigned short* __restrict__ A, int lda,
               const unsigned short* __restrict__ Bt, int ldb,
               int kIters,
               const float* __restrict__ bias,
               unsigned short* __restrict__ apOut,
               float* __restrict__ fOut,
               const int* __restrict__ tki,
               const float* __restrict__ tkp) {
    __shared__ __align__(16) unsigned short As[128 * 32];
    __shared__ __align__(16) unsigned short Bs[128 * 32];

    const int tid  = threadIdx.x;
    const int lane = tid & 63;
    const int wave = tid >> 6;
    const int m0 = blockIdx.y * 128;
    const int n0 = blockIdx.x * 128;
    const int wm = (wave >> 1) * 64;
    const int wn = (wave & 1) * 64;
    const int row16 = lane & 15;
    const int kch   = (lane >> 4) * 8;
    const int quad  = lane >> 4;

    f32x4 acc[4][4] = {};

    // staging geometry: ci = q*256 + tid covers the 128x32 tile row-major,
    // row = ci>>2, kcol = (ci&3)*8 ; LDS dest = wave-uniform base + lane*16B,
    // which equals &As[ci*8] exactly (row-major contiguous in lane order).
    const int r_a  = tid >> 2;              // q=0 row
    const int c_a  = (tid & 3) * 8;         // k offset
    const size_t aRow0 = (size_t)(m0 + r_a) * lda + c_a;
    const size_t bRow0 = (size_t)(n0 + r_a) * ldb + c_a;
    const size_t aRow1 = aRow0 + (size_t)64 * lda;   // q=1: row += 64
    const size_t bRow1 = bRow0 + (size_t)64 * ldb;
    unsigned short* asBase0 = &As[(wave * 64) * 8];
    unsigned short* asBase1 = &As[(256 + wave * 64) * 8];
    unsigned short* bsBase0 = &Bs[(wave * 64) * 8];
    unsigned short* bsBase1 = &Bs[(256 + wave * 64) * 8];

    for (int kt = 0; kt < kIters; ++kt) {
        const int k0 = kt * 32;
        __builtin_amdgcn_global_load_lds(GLOBAL_AS(A + aRow0 + k0), LDS_AS(asBase0), 16, 0, 0);
        __builtin_amdgcn_global_load_lds(GLOBAL_AS(A + aRow1 + k0), LDS_AS(asBase1), 16, 0, 0);
        __builtin_amdgcn_global_load_lds(GLOBAL_AS(Bt + bRow0 + k0), LDS_AS(bsBase0), 16, 0, 0);
        __builtin_amdgcn_global_load_lds(GLOBAL_AS(Bt + bRow1 + k0), LDS_AS(bsBase1), 16, 0, 0);
        __syncthreads();

        bf16x8 af[4], bfr[4];
        #pragma unroll
        for (int mi = 0; mi < 4; ++mi)
            af[mi] = *(const bf16x8*)&As[(wm + mi * 16 + row16) * 32 + kch];
        #pragma unroll
        for (int ni = 0; ni < 4; ++ni)
            bfr[ni] = *(const bf16x8*)&Bs[(wn + ni * 16 + row16) * 32 + kch];

        #pragma unroll
        for (int mi = 0; mi < 4; ++mi)
            #pragma unroll
            for (int ni = 0; ni < 4; ++ni)
                acc[mi][ni] = __builtin_amdgcn_mfma_f32_16x16x32_bf16(
                    af[mi], bfr[ni], acc[mi][ni], 0, 0, 0);
        __syncthreads();
    }

    // epilogue: lane holds col = row16, rows quad*4 + i (i = reg idx)
    #pragma unroll
    for (int mi = 0; mi < 4; ++mi) {
        #pragma unroll
        for (int i = 0; i < 4; ++i) {
            const int m = m0 + wm + mi * 16 + quad * 4 + i;
            int i0 = 0, i1 = 0; float p0 = 0.f, p1 = 0.f;
            if (EPI == 1) {
                i0 = tki[m * 2]; i1 = tki[m * 2 + 1];
                p0 = tkp[m * 2]; p1 = tkp[m * 2 + 1];
            }
            #pragma unroll
            for (int ni = 0; ni < 4; ++ni) {
                const int ncol = n0 + wn + ni * 16 + row16;
                float v = acc[mi][ni][i];
                if (EPI == 0) {
                    v = gelu_exact(v + bias[ncol]);
                    apOut[(size_t)m * KBIG + ncol] = f2bf(v);
                } else if (EPI == 1) {
                    const int e = ncol >> 4;
                    float wt = (i0 == e ? p0 : 0.f) + (i1 == e ? p1 : 0.f);
                    v = gelu_exact(v) * wt;
                    apOut[(size_t)m * KBIG + 3072 + ncol] = f2bf(v);
                } else {
                    fOut[(size_t)m * CDIM + ncol] = v + bias[ncol];
                }
            }
        }
    }
}

// ---------------- launch ----------------

extern "C" void kernel_launch(void* const* d_in, const int* in_sizes, int n_in,
                              void* d_out, int out_size, void* d_ws, size_t ws_size,
                              hipStream_t stream) {
    const float* x   = (const float*)d_in[0];
    const float* tkp = (const float*)d_in[1];
    const int*   tki = (const int*)d_in[2];
    const float* w1  = (const float*)d_in[3];
    const float* b1  = (const float*)d_in[4];
    const float* w2  = (const float*)d_in[5];
    const float* b2  = (const float*)d_in[6];
    const float* wdn = (const float*)d_in[7];
    const float* wup = (const float*)d_in[8];
    float* out = (float*)d_out;

    unsigned short* xb  = (unsigned short*)d_ws;
    unsigned short* w1t = xb  + (size_t)NTOK * CDIM;
    unsigned short* B2t = w1t + (size_t)HIDDIM * CDIM;
    unsigned short* wdt = B2t + (size_t)CDIM * KBIG;
    unsigned short* Ap  = wdt + (size_t)128 * CDIM;

    // casts / layout
    {
        int n4 = (NTOK * CDIM) / 4;
        cast_x_kernel<<<(n4 + 255) / 256, 256, 0, stream>>>(x, xb, n4);
    }
    dim3 tb(32, 8);
    // w1 [768][3072] -> w1t [3072][768]
    transpose_cast_kernel<<<dim3(HIDDIM / 32, CDIM / 32), tb, 0, stream>>>(
        w1, w1t, CDIM, HIDDIM, CDIM, 0);
    // w2 [3072][768] -> B2t[:, 0:3072]
    transpose_cast_kernel<<<dim3(CDIM / 32, HIDDIM / 32), tb, 0, stream>>>(
        w2, B2t, HIDDIM, CDIM, KBIG, 0);
    // w_up flat [128][768] -> B2t[:, 3072:3200]
    transpose_cast_kernel<<<dim3(CDIM / 32, 128 / 32), tb, 0, stream>>>(
        wup, B2t, 128, CDIM, KBIG, 3072);
    pack_wdown_kernel<<<(128 * 768 + 255) / 256, 256, 0, stream>>>(wdn, wdt);

    // GEMMd: sd -> Ap[:, 3072:3200]
    gemm_bt_kernel<1><<<dim3(1, NTOK / 128), 256, 0, stream>>>(
        xb, CDIM, wdt, CDIM, CDIM / 32, nullptr, Ap, nullptr, tki, tkp);
    // GEMM1: h -> Ap[:, 0:3072]
    gemm_bt_kernel<0><<<dim3(HIDDIM / 128, NTOK / 128), 256, 0, stream>>>(
        xb, CDIM, w1t, CDIM, CDIM / 32, b1, Ap, nullptr, nullptr, nullptr);
    // GEMM2: out = Ap @ B2t^T + b2
    gemm_bt_kernel<2><<<dim3(CDIM / 128, NTOK / 128), 256, 0, stream>>>(
        Ap, KBIG, B2t, KBIG, KBIG / 32, b2, nullptr, out, nullptr, nullptr);
}

// Round 3
// 342.418 us; speedup vs baseline: 1.1579x; 1.1454x over previous
//
#include <hip/hip_runtime.h>
#include <hip/hip_bf16.h>
#include <math.h>

// ConvNeXt MLP + parallel MoE-LoRA, fp32 in/out, bf16-tolerance harness.
// B,H,W,C = 64,14,14,768 ; N_tok = 12544 = 98*128 ; HID = 3072 ; E=8,K=2,R=16.
//
//   h  = gelu(x @ w1 + b1)                     GEMM1  [12544,768]x[768,3072]
//   sd[n, e*16+r] = wt[n,e]*gelu(x @ wdown)    GEMMd  [12544,768]x[768,128]
//   out = [h | sd] @ [w2 ; wup_flat] + b2      GEMM2  [12544,3200]x[3200,768]
//
// R3: (1) branch-free tanh-form GELU in epilogues (erff libm call was ~40+
//     VALU inst/elem x 64 elem/thread — dominated GEMM1's short-K kernel);
//     (2) GEMM2 XCD swizzle: same-A-row blocks share L&7 so the 0.8 MB A-strip
//     stays in one XCD's L2 instead of being pulled into 6 XCDs via L3.

#define NTOK   12544
#define CDIM   768
#define HIDDIM 3072
#define KBIG   3200

typedef __attribute__((ext_vector_type(8))) short bf16x8;
typedef __attribute__((ext_vector_type(4))) float f32x4;

#define GLOBAL_AS(p) ((const __attribute__((address_space(1))) void*)(p))
#define LDS_AS(p)    ((__attribute__((address_space(3))) void*)(p))

__device__ inline unsigned short f2bf(float f) {
    unsigned int x = __float_as_uint(f);
    x += 0x7fffu + ((x >> 16) & 1u);   // RNE
    return (unsigned short)(x >> 16);
}

// tanh-form GELU, branch-free. gelu(x) ~= x * sigmoid(2u), u = sqrt(2/pi)(x+0.044715x^3).
// max |err| vs exact erf form ~4.3e-4 — negligible vs bf16 storage error downstream.
__device__ inline float gelu_fast(float x) {
    float x3 = x * x * x;
    float u2 = 1.5957691216057308f * x + 0.07135481627260025f * x3;  // 2u
    float e = __expf(-u2);                       // v_exp_f32; underflow/overflow safe
    return x * __builtin_amdgcn_rcpf(1.0f + e);  // x * sigmoid(2u)
}

// ---------------- cast / layout kernels ----------------

__global__ void cast_x_kernel(const float* __restrict__ in,
                              unsigned short* __restrict__ out, int n4) {
    int i = blockIdx.x * 256 + threadIdx.x;
    if (i >= n4) return;
    float4 v = ((const float4*)in)[i];
    ushort4 o;
    o.x = f2bf(v.x); o.y = f2bf(v.y); o.z = f2bf(v.z); o.w = f2bf(v.w);
    ((ushort4*)out)[i] = o;
}

// out[(c0+i)][out_off + r0+tx] = in[(r0+tx)][(c0+i)]  — 32x32 LDS tile transpose
__global__ void transpose_cast_kernel(const float* __restrict__ in,
                                      unsigned short* __restrict__ out,
                                      int R, int Ccols, int out_ld, int out_off) {
    __shared__ float tile[32][33];
    int c0 = blockIdx.x * 32, r0 = blockIdx.y * 32;
    int tx = threadIdx.x, ty = threadIdx.y;
    for (int i = ty; i < 32; i += 8)
        tile[i][tx] = in[(size_t)(r0 + i) * Ccols + c0 + tx];
    __syncthreads();
    for (int i = ty; i < 32; i += 8)
        out[(size_t)(c0 + i) * out_ld + out_off + r0 + tx] = f2bf(tile[tx][i]);
}

// wdt[j][c] = w_down[e][c][r]  (j = e*16+r), w_down is [8][768][16] row-major
__global__ void pack_wdown_kernel(const float* __restrict__ in,
                                  unsigned short* __restrict__ out) {
    int idx = blockIdx.x * 256 + threadIdx.x;
    if (idx >= 128 * 768) return;
    int j = idx / 768, c = idx - j * 768;
    int e = j >> 4, r = j & 15;
    out[idx] = f2bf(in[((size_t)e * 768 + c) * 16 + r]);
}

// ---------------- MFMA GEMM, C = A * Bt^T, 128x128 tile, BK=32 ----------------
// EPI 0: h-epilogue   -> gelu(acc + b1[n]) -> bf16 Ap[m*3200 + n]
// EPI 1: down-epilogue-> wt[m, n>>4]*gelu(acc) -> bf16 Ap[m*3200 + 3072 + n]
// EPI 2: out-epilogue -> acc + b2[n] -> f32 out[m*768 + n]  (1-D grid + XCD swizzle)

template <int EPI>
__global__ void __launch_bounds__(256)
gemm_bt_kernel(const unsigned short* __restrict__ A, int lda,
               const unsigned short* __restrict__ Bt, int ldb,
               int kIters,
               const float* __restrict__ bias,
               unsigned short* __restrict__ apOut,
               float* __restrict__ fOut,
               const int* __restrict__ tki,
               const float* __restrict__ tkp) {
    __shared__ __align__(16) unsigned short As[128 * 32];
    __shared__ __align__(16) unsigned short Bs[128 * 32];

    int bx, by;
    if (EPI == 2) {
        // 1-D grid, 624 blocks. Same-row (by) blocks share L&7 -> same XCD
        // (empirical round-robin), consecutive in its stream -> A-strip L2-resident.
        int L = blockIdx.x;
        int k = L & 7, t = L >> 3;
        bx = t % 6;
        by = (t / 6) * 8 + k;
        if (by >= NTOK / 128) return;      // block-uniform -> safe before barriers
    } else {
        bx = blockIdx.x;
        by = blockIdx.y;
    }

    const int tid  = threadIdx.x;
    const int wave = tid >> 6;
    const int lane = tid & 63;
    const int m0 = by * 128;
    const int n0 = bx * 128;
    const int wm = (wave >> 1) * 64;
    const int wn = (wave & 1) * 64;
    const int row16 = lane & 15;
    const int kch   = (lane >> 4) * 8;
    const int quad  = lane >> 4;

    f32x4 acc[4][4] = {};

    // staging: ci = q*256 + tid covers the 128x32 tile row-major (row=ci>>2,
    // kcol=(ci&3)*8); global_load_lds dest = wave-uniform base + lane*16B = &As[ci*8].
    const int r_a  = tid >> 2;
    const int c_a  = (tid & 3) * 8;
    const size_t aRow0 = (size_t)(m0 + r_a) * lda + c_a;
    const size_t bRow0 = (size_t)(n0 + r_a) * ldb + c_a;
    const size_t aRow1 = aRow0 + (size_t)64 * lda;
    const size_t bRow1 = bRow0 + (size_t)64 * ldb;
    unsigned short* asBase0 = &As[(wave * 64) * 8];
    unsigned short* asBase1 = &As[(256 + wave * 64) * 8];
    unsigned short* bsBase0 = &Bs[(wave * 64) * 8];
    unsigned short* bsBase1 = &Bs[(256 + wave * 64) * 8];

    for (int kt = 0; kt < kIters; ++kt) {
        const int k0 = kt * 32;
        __builtin_amdgcn_global_load_lds(GLOBAL_AS(A + aRow0 + k0), LDS_AS(asBase0), 16, 0, 0);
        __builtin_amdgcn_global_load_lds(GLOBAL_AS(A + aRow1 + k0), LDS_AS(asBase1), 16, 0, 0);
        __builtin_amdgcn_global_load_lds(GLOBAL_AS(Bt + bRow0 + k0), LDS_AS(bsBase0), 16, 0, 0);
        __builtin_amdgcn_global_load_lds(GLOBAL_AS(Bt + bRow1 + k0), LDS_AS(bsBase1), 16, 0, 0);
        __syncthreads();

        bf16x8 af[4], bfr[4];
        #pragma unroll
        for (int mi = 0; mi < 4; ++mi)
            af[mi] = *(const bf16x8*)&As[(wm + mi * 16 + row16) * 32 + kch];
        #pragma unroll
        for (int ni = 0; ni < 4; ++ni)
            bfr[ni] = *(const bf16x8*)&Bs[(wn + ni * 16 + row16) * 32 + kch];

        #pragma unroll
        for (int mi = 0; mi < 4; ++mi)
            #pragma unroll
            for (int ni = 0; ni < 4; ++ni)
                acc[mi][ni] = __builtin_amdgcn_mfma_f32_16x16x32_bf16(
                    af[mi], bfr[ni], acc[mi][ni], 0, 0, 0);
        __syncthreads();
    }

    // epilogue: lane holds col = row16, rows quad*4 + i (i = reg idx)
    #pragma unroll
    for (int mi = 0; mi < 4; ++mi) {
        #pragma unroll
        for (int i = 0; i < 4; ++i) {
            const int m = m0 + wm + mi * 16 + quad * 4 + i;
            int i0 = 0, i1 = 0; float p0 = 0.f, p1 = 0.f;
            if (EPI == 1) {
                i0 = tki[m * 2]; i1 = tki[m * 2 + 1];
                p0 = tkp[m * 2]; p1 = tkp[m * 2 + 1];
            }
            #pragma unroll
            for (int ni = 0; ni < 4; ++ni) {
                const int ncol = n0 + wn + ni * 16 + row16;
                float v = acc[mi][ni][i];
                if (EPI == 0) {
                    v = gelu_fast(v + bias[ncol]);
                    apOut[(size_t)m * KBIG + ncol] = f2bf(v);
                } else if (EPI == 1) {
                    const int e = ncol >> 4;
                    float wt = (i0 == e ? p0 : 0.f) + (i1 == e ? p1 : 0.f);
                    v = gelu_fast(v) * wt;
                    apOut[(size_t)m * KBIG + 3072 + ncol] = f2bf(v);
                } else {
                    fOut[(size_t)m * CDIM + ncol] = v + bias[ncol];
                }
            }
        }
    }
}

// ---------------- launch ----------------

extern "C" void kernel_launch(void* const* d_in, const int* in_sizes, int n_in,
                              void* d_out, int out_size, void* d_ws, size_t ws_size,
                              hipStream_t stream) {
    const float* x   = (const float*)d_in[0];
    const float* tkp = (const float*)d_in[1];
    const int*   tki = (const int*)d_in[2];
    const float* w1  = (const float*)d_in[3];
    const float* b1  = (const float*)d_in[4];
    const float* w2  = (const float*)d_in[5];
    const float* b2  = (const float*)d_in[6];
    const float* wdn = (const float*)d_in[7];
    const float* wup = (const float*)d_in[8];
    float* out = (float*)d_out;

    unsigned short* xb  = (unsigned short*)d_ws;
    unsigned short* w1t = xb  + (size_t)NTOK * CDIM;
    unsigned short* B2t = w1t + (size_t)HIDDIM * CDIM;
    unsigned short* wdt = B2t + (size_t)CDIM * KBIG;
    unsigned short* Ap  = wdt + (size_t)128 * CDIM;

    {
        int n4 = (NTOK * CDIM) / 4;
        cast_x_kernel<<<(n4 + 255) / 256, 256, 0, stream>>>(x, xb, n4);
    }
    dim3 tb(32, 8);
    // w1 [768][3072] -> w1t [3072][768]
    transpose_cast_kernel<<<dim3(HIDDIM / 32, CDIM / 32), tb, 0, stream>>>(
        w1, w1t, CDIM, HIDDIM, CDIM, 0);
    // w2 [3072][768] -> B2t[:, 0:3072]
    transpose_cast_kernel<<<dim3(CDIM / 32, HIDDIM / 32), tb, 0, stream>>>(
        w2, B2t, HIDDIM, CDIM, KBIG, 0);
    // w_up flat [128][768] -> B2t[:, 3072:3200]
    transpose_cast_kernel<<<dim3(CDIM / 32, 128 / 32), tb, 0, stream>>>(
        wup, B2t, 128, CDIM, KBIG, 3072);
    pack_wdown_kernel<<<(128 * 768 + 255) / 256, 256, 0, stream>>>(wdn, wdt);

    // GEMMd: sd -> Ap[:, 3072:3200]
    gemm_bt_kernel<1><<<dim3(1, NTOK / 128), 256, 0, stream>>>(
        xb, CDIM, wdt, CDIM, CDIM / 32, nullptr, Ap, nullptr, tki, tkp);
    // GEMM1: h -> Ap[:, 0:3072]
    gemm_bt_kernel<0><<<dim3(HIDDIM / 128, NTOK / 128), 256, 0, stream>>>(
        xb, CDIM, w1t, CDIM, CDIM / 32, b1, Ap, nullptr, nullptr, nullptr);
    // GEMM2: out = Ap @ B2t^T + b2 ; 1-D swizzled grid: 6 x-tiles * 104 padded rows / 8
    gemm_bt_kernel<2><<<dim3(624), 256, 0, stream>>>(
        Ap, KBIG, B2t, KBIG, KBIG / 32, b2, nullptr, out, nullptr, nullptr);
}